// Round 16
// baseline (179.858 us; speedup 1.0000x reference)
//
#include <hip/hip_runtime.h>
#include <hip/hip_bf16.h>
#include <math.h>

// Problem constants
#define B_  2
#define N_  6
#define C_  64
#define FH_ 16
#define FW_ 44
#define D_  64
#define PIX (FH_*FW_)          // 704
#define BNI (B_*N_)            // 12
#define NPILLAR (BNI*PIX)      // 8448
#define NPOINT (NPILLAR*D_)    // 540672
#define BEVH 128
#define BEVW 128
#define BEVC (BEVH*BEVW)       // 16384
#define NCELL (B_*BEVC)        // 32768
#define PW 46                  // padded plane width
#define PP (18*PW)             // padded plane = 828 floats

typedef unsigned int u32;

__device__ __forceinline__ int rlane_i(int v, int l) {
    return __builtin_amdgcn_readlane(v, l);
}
__device__ __forceinline__ float rlane_f(float v, int l) {
    return __int_as_float(__builtin_amdgcn_readlane(__float_as_int(v), l));
}

// ---------------------------------------------------------------------------
// K1: fused init + conv1.
// blocks [0,768): conv1 (4-way cin-split, 16-plane float4 staging, 1 barrier)
// blocks [768,900): LDS-tiled transpose feat -> x_t
// block 900: w2 transpose + fused M = R*inv(K)
// blocks [901,1029): zero spool (2.1M floats, float4-wide)
// ---------------------------------------------------------------------------
__global__ __launch_bounds__(256) void k_init_conv(const float* __restrict__ feat,
                                                   const float* __restrict__ w1,
                                                   float* __restrict__ hpAll,
                                                   float* __restrict__ x_t,
                                                   const float* __restrict__ w2,
                                                   float* __restrict__ w2t,
                                                   float* __restrict__ spool,
                                                   const float* __restrict__ intr,
                                                   const float* __restrict__ extr,
                                                   double* __restrict__ Mbuf) {
    const int blk = blockIdx.x;
    const int tid = threadIdx.x;

    __shared__ float smem[16 * PP];          // 52,992 B (3 blocks/CU)

    if (blk < 768) {
        const int bn = blk >> 6;
        const int ch = (blk >> 4) & 3;
        const int o0 = (blk & 15) * 4;
        const int c0 = ch * 16;

        for (int t = tid; t < 4 * PP; t += 256)
            ((float4*)smem)[t] = make_float4(0.f, 0.f, 0.f, 0.f);
        __syncthreads();

        const float4* fb4 = (const float4*)(feat + ((size_t)bn * C_ + c0) * PIX);
#pragma unroll
        for (int k = 0; k < 11; ++k) {
            const int j = k * 256 + tid;     // < 2816 = 16*176
            const int pl = j / 176;
            const int r  = j % 176;
            const int row = r / 11, q = r % 11;
            const float4 v = fb4[j];
            float* dstp = &smem[pl * PP + (row + 1) * PW + q * 4 + 1];
            dstp[0] = v.x; dstp[1] = v.y; dstp[2] = v.z; dstp[3] = v.w;
        }
        __syncthreads();                      // the ONLY compute barrier

        const int y0 = tid / FW_,          x0 = tid % FW_;
        const int y1 = (tid + 256) / FW_,  x1 = (tid + 256) % FW_;
        const int y2 = (tid + 512) / FW_,  x2 = (tid + 512) % FW_;
        const int rp0 = y0 * PW + x0;
        const int rp1 = y1 * PW + x1;
        const int rp2 = y2 * PW + x2;

        float a00=0,a01=0,a02=0,a03=0, a10=0,a11=0,a12=0,a13=0,
              a20=0,a21=0,a22=0,a23=0;
#pragma unroll 4
        for (int i = 0; i < 16; ++i) {
            const float* wr0 = w1 + ((size_t)(o0 + 0) * C_ + c0 + i) * 9;
            const float* wr1 = w1 + ((size_t)(o0 + 1) * C_ + c0 + i) * 9;
            const float* wr2 = w1 + ((size_t)(o0 + 2) * C_ + c0 + i) * 9;
            const float* wr3 = w1 + ((size_t)(o0 + 3) * C_ + c0 + i) * 9;
            const float* pb = &smem[i * PP];
#define CONV_SLOT(RP, A0, A1, A2, A3)                                          \
    {                                                                          \
        const float* bb = pb + (RP);                                           \
        const float n0=bb[0], n1=bb[1], n2=bb[2];                              \
        const float n3=bb[PW], n4=bb[PW+1], n5=bb[PW+2];                       \
        const float n6=bb[2*PW], n7=bb[2*PW+1], n8=bb[2*PW+2];                 \
        A0 += n0*wr0[0]+n1*wr0[1]+n2*wr0[2]+n3*wr0[3]+n4*wr0[4]                \
            + n5*wr0[5]+n6*wr0[6]+n7*wr0[7]+n8*wr0[8];                         \
        A1 += n0*wr1[0]+n1*wr1[1]+n2*wr1[2]+n3*wr1[3]+n4*wr1[4]                \
            + n5*wr1[5]+n6*wr1[6]+n7*wr1[7]+n8*wr1[8];                         \
        A2 += n0*wr2[0]+n1*wr2[1]+n2*wr2[2]+n3*wr2[3]+n4*wr2[4]                \
            + n5*wr2[5]+n6*wr2[6]+n7*wr2[7]+n8*wr2[8];                         \
        A3 += n0*wr3[0]+n1*wr3[1]+n2*wr3[2]+n3*wr3[3]+n4*wr3[4]                \
            + n5*wr3[5]+n6*wr3[6]+n7*wr3[7]+n8*wr3[8];                         \
    }
            CONV_SLOT(rp0, a00, a01, a02, a03);
            CONV_SLOT(rp1, a10, a11, a12, a13);
            if (tid < PIX - 512) CONV_SLOT(rp2, a20, a21, a22, a23);
#undef CONV_SLOT
        }
        float* hp = hpAll + (size_t)ch * NPOINT + (size_t)bn * PIX * C_;
        *(float4*)&hp[(size_t)tid * C_ + o0]         = make_float4(a00,a01,a02,a03);
        *(float4*)&hp[(size_t)(tid + 256) * C_ + o0] = make_float4(a10,a11,a12,a13);
        if (tid < PIX - 512)
            *(float4*)&hp[(size_t)(tid + 512) * C_ + o0] = make_float4(a20,a21,a22,a23);
    } else if (blk < 900) {
        const int u  = blk - 768;
        const int bn = u / 11;
        const int p0 = (u % 11) * 64;
        const int lane = tid & 63;
        const int row4 = tid >> 6;
        float* tile = smem;                   // [64][65]
#pragma unroll
        for (int k = 0; k < 16; ++k) {
            const int c = k * 4 + row4;
            tile[c * 65 + lane] = feat[((size_t)bn * C_ + c) * PIX + p0 + lane];
        }
        __syncthreads();
#pragma unroll
        for (int k = 0; k < 16; ++k) {
            const int r = k * 4 + row4;
            x_t[((size_t)bn * PIX + p0 + r) * C_ + lane] = tile[lane * 65 + r];
        }
    } else if (blk == 900) {
#pragma unroll
        for (int k = 0; k < 16; ++k) {
            const int idx = k * 256 + tid;
            const int d = idx >> 6, c = idx & 63;
            w2t[c * D_ + d] = w2[idx];
        }
        if (tid < BNI) {
            const float* K = &intr[tid * 9];
            const double a00 = K[0], a01 = K[1], a02 = K[2];
            const double a10 = K[3], a11 = K[4], a12 = K[5];
            const double a20 = K[6], a21 = K[7], a22 = K[8];
            const double det = a00 * (a11 * a22 - a12 * a21)
                             - a01 * (a10 * a22 - a12 * a20)
                             + a02 * (a10 * a21 - a11 * a20);
            const double id = 1.0 / det;
            double inv[9];
            inv[0] = (a11 * a22 - a12 * a21) * id;
            inv[1] = (a02 * a21 - a01 * a22) * id;
            inv[2] = (a01 * a12 - a02 * a11) * id;
            inv[3] = (a12 * a20 - a10 * a22) * id;
            inv[4] = (a00 * a22 - a02 * a20) * id;
            inv[5] = (a02 * a10 - a00 * a12) * id;
            inv[6] = (a10 * a21 - a11 * a20) * id;
            inv[7] = (a01 * a20 - a00 * a21) * id;
            inv[8] = (a00 * a11 - a01 * a10) * id;
            const float* E = &extr[tid * 16];
            double* M = &Mbuf[tid * 9];
            for (int r = 0; r < 3; ++r) {
                const double r0 = E[r*4+0], r1 = E[r*4+1], r2 = E[r*4+2];
                M[r*3+0] = r0*inv[0] + r1*inv[3] + r2*inv[6];
                M[r*3+1] = r0*inv[1] + r1*inv[4] + r2*inv[7];
                M[r*3+2] = r0*inv[2] + r1*inv[5] + r2*inv[8];
            }
        }
    } else {
        // zero spool: 2,097,152 floats = 524,288 float4 over 128 blocks
        const int u = blk - 901;
        float4* sp4 = (float4*)spool;
#pragma unroll
        for (int k = 0; k < 16; ++k)
            sp4[(size_t)u * 4096 + k * 256 + tid] = make_float4(0.f, 0.f, 0.f, 0.f);
    }
}

// ---------------------------------------------------------------------------
// K2: depth + direct coalesced scatter.
// Per wave = one pillar (lane = depth bin for softmax/geometry, lane =
// channel for the scatter). After computing per-lane (cell, w), the wave
// loads its pillar's x-row ONCE and fires 64 coalesced 256B atomicAdds
// (4 cache lines each), wave-uniform branch on validity. No counts, no
// sort, no fences.
// ---------------------------------------------------------------------------
__global__ __launch_bounds__(256) void k_depth_scatter(const float* __restrict__ hpAll,
                                                       const float* __restrict__ b1,
                                                       const float* __restrict__ gma,
                                                       const float* __restrict__ bta,
                                                       const float* __restrict__ mu,
                                                       const float* __restrict__ var,
                                                       const float* __restrict__ w2t,
                                                       const float* __restrict__ b2,
                                                       const double* __restrict__ Mbuf,
                                                       const float* __restrict__ extr,
                                                       const float* __restrict__ x_t,
                                                       float* __restrict__ spool) {
    const int tid  = threadIdx.x;
    const int wv   = tid >> 6;
    const int lane = tid & 63;
    const int pillar = blockIdx.x * 4 + wv;
    const int bn = pillar / PIX;
    const int p  = pillar % PIX;
    const int yi = p / FW_;
    const int xi = p % FW_;

    __shared__ float w2s[C_ * D_];           // 16 KB, layout [c][d]
#pragma unroll
    for (int k = 0; k < 4; ++k)
        ((float4*)w2s)[k * 256 + tid] = ((const float4*)w2t)[k * 256 + tid];

    // h for channel `lane` of this wave's pillar
    float h;
    {
        const size_t o = (size_t)pillar * C_ + lane;
        h = hpAll[o] + hpAll[NPOINT + o] + hpAll[2 * (size_t)NPOINT + o]
          + hpAll[3 * (size_t)NPOINT + o] + b1[lane];
        const float sc = gma[lane] / sqrtf(var[lane] + 1e-5f);
        h = (h - mu[lane]) * sc + bta[lane];
        h = h > 0.f ? h : 0.f;
    }
    __syncthreads();                          // w2s ready

    // logit[lane] = b2 + sum_c h[c] * w2t[c][lane]
    float l0 = 0.f, l1 = 0.f, l2 = 0.f, l3 = 0.f;
#pragma unroll
    for (int c = 0; c < C_; c += 4) {
        l0 += rlane_f(h, c + 0) * w2s[(c + 0) * D_ + lane];
        l1 += rlane_f(h, c + 1) * w2s[(c + 1) * D_ + lane];
        l2 += rlane_f(h, c + 2) * w2s[(c + 2) * D_ + lane];
        l3 += rlane_f(h, c + 3) * w2s[(c + 3) * D_ + lane];
    }
    const float logit = b2[lane] + ((l0 + l1) + (l2 + l3));

    float m = logit;
#pragma unroll
    for (int off = 32; off; off >>= 1) m = fmaxf(m, __shfl_xor(m, off));
    float e = expf(logit - m);
    float s = e;
#pragma unroll
    for (int off = 32; off; off >>= 1) s += __shfl_xor(s, off);
    const float wval = e / s;

    // geometry (lane = depth bin)
    const double* M = &Mbuf[bn * 9];
    const double xn = (double)xi * (703.0 / 43.0);
    const double yn = (double)yi * 17.0;
    const double vx = M[0] * xn + M[1] * yn + M[2];
    const double vy = M[3] * xn + M[4] * yn + M[5];
    const double dd = 1.0 + (double)lane * (59.0 / 63.0);
    const float* E = &extr[bn * 16];
    const double ex = dd * vx + (double)E[3];
    const double ey = dd * vy + (double)E[7];
    const int ix = (int)floor((ex + 51.2) * 1.25);
    const int iy = (int)floor((ey + 51.2) * 1.25);
    const bool valid = (ix >= 0) && (ix < BEVW) && (iy >= 0) && (iy < BEVH);
    const int cellv = valid ? ((bn / N_) * BEVC + iy * BEVW + ix) : -1;

    // coalesced scatter: lane = channel now
    const float xv = x_t[(size_t)pillar * C_ + lane];

#pragma unroll 8
    for (int t = 0; t < 64; ++t) {
        const int cc = rlane_i(cellv, t);     // wave-uniform
        if (cc >= 0) {
            const float wt = rlane_f(wval, t);
            atomicAdd(&spool[(size_t)cc * C_ + lane], wt * xv);
        }
    }
}

// ---------------------------------------------------------------------------
// K3: output transpose spool[b][cell][c] -> out[b][c][cell].
// ---------------------------------------------------------------------------
__global__ __launch_bounds__(256) void k_out(const float* __restrict__ spool,
                                             float* __restrict__ out) {
    const int tile_i = blockIdx.x;            // 0..511
    const int b  = tile_i >> 8;
    const int c0 = (tile_i & 255) * 64;       // cell base
    const int tid = threadIdx.x;
    const int lane = tid & 63;
    const int row4 = tid >> 6;

    __shared__ float tile[64][65];
#pragma unroll
    for (int k = 0; k < 16; ++k) {
        const int r = k * 4 + row4;
        tile[r][lane] = spool[((size_t)b * BEVC + c0 + r) * C_ + lane];
    }
    __syncthreads();
#pragma unroll
    for (int k = 0; k < 16; ++k) {
        const int ch = k * 4 + row4;
        out[((size_t)b * C_ + ch) * BEVC + c0 + lane] = tile[lane][ch];
    }
}

// ---------------------------------------------------------------------------
extern "C" void kernel_launch(void* const* d_in, const int* in_sizes, int n_in,
                              void* d_out, int out_size, void* d_ws, size_t ws_size,
                              hipStream_t stream) {
    const float* feat  = (const float*)d_in[0];
    const float* intr  = (const float*)d_in[1];
    const float* extr  = (const float*)d_in[2];
    const float* w1    = (const float*)d_in[3];
    const float* b1    = (const float*)d_in[4];
    const float* gma   = (const float*)d_in[5];
    const float* bta   = (const float*)d_in[6];
    const float* mu    = (const float*)d_in[7];
    const float* var   = (const float*)d_in[8];
    const float* w2    = (const float*)d_in[9];
    const float* b2    = (const float*)d_in[10];
    float* out = (float*)d_out;

    // workspace layout
    double* Mbuf  = (double*)d_ws;                                   // 864 B
    float*  x_t   = (float*)((char*)d_ws + 1024);                    // NPOINT
    float*  hpAll = x_t + NPOINT;                                    // 4*NPOINT
    float*  spool = hpAll + 4 * (size_t)NPOINT;                      // NCELL*64
    float*  w2t   = spool + (size_t)NCELL * C_;                      // 4096

    k_init_conv<<<1029, 256, 0, stream>>>(feat, w1, hpAll, x_t, w2, w2t,
                                          spool, intr, extr, Mbuf);
    k_depth_scatter<<<NPILLAR / 4, 256, 0, stream>>>(hpAll, b1, gma, bta, mu,
                                                     var, w2t, b2, Mbuf, extr,
                                                     x_t, spool);
    k_out<<<512, 256, 0, stream>>>(spool, out);

    (void)in_sizes; (void)n_in; (void)ws_size; (void)out_size;
}

// Round 17
// 88.291 us; speedup vs baseline: 2.0371x; 2.0371x over previous
//
#include <hip/hip_runtime.h>
#include <hip/hip_bf16.h>
#include <math.h>

// Problem constants
#define B_  2
#define N_  6
#define C_  64
#define FH_ 16
#define FW_ 44
#define D_  64
#define PIX (FH_*FW_)          // 704
#define BNI (B_*N_)            // 12
#define NPILLAR (BNI*PIX)      // 8448
#define NPOINT (NPILLAR*D_)    // 540672
#define BEVH 128
#define BEVW 128
#define BEVC (BEVH*BEVW)       // 16384
#define NCELL (B_*BEVC)        // 32768
#define PW 46                  // padded plane width
#define PP (18*PW)             // padded plane = 828 floats

typedef unsigned int u32;
typedef unsigned long long u64;

__device__ __forceinline__ int rlane_i(int v, int l) {
    return __builtin_amdgcn_readlane(v, l);
}
__device__ __forceinline__ float rlane_f(float v, int l) {
    return __int_as_float(__builtin_amdgcn_readlane(__float_as_int(v), l));
}

// ---------------------------------------------------------------------------
// K1: fused init + conv1 (R12/R14-proven: 4-way cin-split, 768 conv blocks,
// single 16-plane float4 staging, 1 barrier).
// ---------------------------------------------------------------------------
__global__ __launch_bounds__(256) void k_init_conv(const float* __restrict__ feat,
                                                   const float* __restrict__ w1,
                                                   float* __restrict__ hpAll,
                                                   float* __restrict__ x_t,
                                                   const float* __restrict__ w2,
                                                   float* __restrict__ w2t,
                                                   u32* __restrict__ counts,
                                                   u32* __restrict__ gcursor,
                                                   const float* __restrict__ intr,
                                                   const float* __restrict__ extr,
                                                   double* __restrict__ Mbuf) {
    const int blk = blockIdx.x;
    const int tid = threadIdx.x;

    __shared__ float smem[16 * PP];          // 52,992 B (3 blocks/CU)

    if (blk < 768) {
        if (blk < 128) counts[blk * 256 + tid] = 0u;

        const int bn = blk >> 6;
        const int ch = (blk >> 4) & 3;
        const int o0 = (blk & 15) * 4;
        const int c0 = ch * 16;

        for (int t = tid; t < 4 * PP; t += 256)
            ((float4*)smem)[t] = make_float4(0.f, 0.f, 0.f, 0.f);
        __syncthreads();

        const float4* fb4 = (const float4*)(feat + ((size_t)bn * C_ + c0) * PIX);
#pragma unroll
        for (int k = 0; k < 11; ++k) {
            const int j = k * 256 + tid;     // < 2816 = 16*176
            const int pl = j / 176;
            const int r  = j % 176;
            const int row = r / 11, q = r % 11;
            const float4 v = fb4[j];
            float* dstp = &smem[pl * PP + (row + 1) * PW + q * 4 + 1];
            dstp[0] = v.x; dstp[1] = v.y; dstp[2] = v.z; dstp[3] = v.w;
        }
        __syncthreads();                      // the ONLY compute barrier

        const int y0 = tid / FW_,          x0 = tid % FW_;
        const int y1 = (tid + 256) / FW_,  x1 = (tid + 256) % FW_;
        const int y2 = (tid + 512) / FW_,  x2 = (tid + 512) % FW_;
        const int rp0 = y0 * PW + x0;
        const int rp1 = y1 * PW + x1;
        const int rp2 = y2 * PW + x2;

        float a00=0,a01=0,a02=0,a03=0, a10=0,a11=0,a12=0,a13=0,
              a20=0,a21=0,a22=0,a23=0;
#pragma unroll 4
        for (int i = 0; i < 16; ++i) {
            const float* wr0 = w1 + ((size_t)(o0 + 0) * C_ + c0 + i) * 9;
            const float* wr1 = w1 + ((size_t)(o0 + 1) * C_ + c0 + i) * 9;
            const float* wr2 = w1 + ((size_t)(o0 + 2) * C_ + c0 + i) * 9;
            const float* wr3 = w1 + ((size_t)(o0 + 3) * C_ + c0 + i) * 9;
            const float* pb = &smem[i * PP];
#define CONV_SLOT(RP, A0, A1, A2, A3)                                          \
    {                                                                          \
        const float* bb = pb + (RP);                                           \
        const float n0=bb[0], n1=bb[1], n2=bb[2];                              \
        const float n3=bb[PW], n4=bb[PW+1], n5=bb[PW+2];                       \
        const float n6=bb[2*PW], n7=bb[2*PW+1], n8=bb[2*PW+2];                 \
        A0 += n0*wr0[0]+n1*wr0[1]+n2*wr0[2]+n3*wr0[3]+n4*wr0[4]                \
            + n5*wr0[5]+n6*wr0[6]+n7*wr0[7]+n8*wr0[8];                         \
        A1 += n0*wr1[0]+n1*wr1[1]+n2*wr1[2]+n3*wr1[3]+n4*wr1[4]                \
            + n5*wr1[5]+n6*wr1[6]+n7*wr1[7]+n8*wr1[8];                         \
        A2 += n0*wr2[0]+n1*wr2[1]+n2*wr2[2]+n3*wr2[3]+n4*wr2[4]                \
            + n5*wr2[5]+n6*wr2[6]+n7*wr2[7]+n8*wr2[8];                         \
        A3 += n0*wr3[0]+n1*wr3[1]+n2*wr3[2]+n3*wr3[3]+n4*wr3[4]                \
            + n5*wr3[5]+n6*wr3[6]+n7*wr3[7]+n8*wr3[8];                         \
    }
            CONV_SLOT(rp0, a00, a01, a02, a03);
            CONV_SLOT(rp1, a10, a11, a12, a13);
            if (tid < PIX - 512) CONV_SLOT(rp2, a20, a21, a22, a23);
#undef CONV_SLOT
        }
        float* hp = hpAll + (size_t)ch * NPOINT + (size_t)bn * PIX * C_;
        *(float4*)&hp[(size_t)tid * C_ + o0]         = make_float4(a00,a01,a02,a03);
        *(float4*)&hp[(size_t)(tid + 256) * C_ + o0] = make_float4(a10,a11,a12,a13);
        if (tid < PIX - 512)
            *(float4*)&hp[(size_t)(tid + 512) * C_ + o0] = make_float4(a20,a21,a22,a23);
    } else if (blk < 900) {
        const int u  = blk - 768;
        const int bn = u / 11;
        const int p0 = (u % 11) * 64;
        const int lane = tid & 63;
        const int row4 = tid >> 6;
        float* tile = smem;                   // [64][65]
#pragma unroll
        for (int k = 0; k < 16; ++k) {
            const int c = k * 4 + row4;
            tile[c * 65 + lane] = feat[((size_t)bn * C_ + c) * PIX + p0 + lane];
        }
        __syncthreads();
#pragma unroll
        for (int k = 0; k < 16; ++k) {
            const int r = k * 4 + row4;
            x_t[((size_t)bn * PIX + p0 + r) * C_ + lane] = tile[lane * 65 + r];
        }
    } else {
#pragma unroll
        for (int k = 0; k < 16; ++k) {
            const int idx = k * 256 + tid;
            const int d = idx >> 6, c = idx & 63;
            w2t[c * D_ + d] = w2[idx];
        }
        if (tid == 0) *gcursor = 0u;
        if (tid < BNI) {
            const float* K = &intr[tid * 9];
            const double a00 = K[0], a01 = K[1], a02 = K[2];
            const double a10 = K[3], a11 = K[4], a12 = K[5];
            const double a20 = K[6], a21 = K[7], a22 = K[8];
            const double det = a00 * (a11 * a22 - a12 * a21)
                             - a01 * (a10 * a22 - a12 * a20)
                             + a02 * (a10 * a21 - a11 * a20);
            const double id = 1.0 / det;
            double inv[9];
            inv[0] = (a11 * a22 - a12 * a21) * id;
            inv[1] = (a02 * a21 - a01 * a22) * id;
            inv[2] = (a01 * a12 - a02 * a11) * id;
            inv[3] = (a12 * a20 - a10 * a22) * id;
            inv[4] = (a00 * a22 - a02 * a20) * id;
            inv[5] = (a02 * a10 - a00 * a12) * id;
            inv[6] = (a10 * a21 - a11 * a20) * id;
            inv[7] = (a01 * a20 - a00 * a21) * id;
            inv[8] = (a00 * a11 - a01 * a10) * id;
            const float* E = &extr[tid * 16];
            double* M = &Mbuf[tid * 9];
            for (int r = 0; r < 3; ++r) {
                const double r0 = E[r*4+0], r1 = E[r*4+1], r2 = E[r*4+2];
                M[r*3+0] = r0*inv[0] + r1*inv[3] + r2*inv[6];
                M[r*3+1] = r0*inv[1] + r1*inv[4] + r2*inv[7];
                M[r*3+2] = r0*inv[2] + r1*inv[5] + r2*inv[8];
            }
        }
    }
}

// ---------------------------------------------------------------------------
// K2: depth (R14-proven: LDS w2t + readlane h + 4 accumulators, no fences).
// ---------------------------------------------------------------------------
__global__ __launch_bounds__(256) void k_depth(const float* __restrict__ hpAll,
                                               const float* __restrict__ b1,
                                               const float* __restrict__ gma,
                                               const float* __restrict__ bta,
                                               const float* __restrict__ mu,
                                               const float* __restrict__ var,
                                               const float* __restrict__ w2t,
                                               const float* __restrict__ b2,
                                               const double* __restrict__ Mbuf,
                                               const float* __restrict__ extr,
                                               uint2* __restrict__ pc,
                                               u32* __restrict__ counts) {
    const int tid  = threadIdx.x;
    const int wv   = tid >> 6;
    const int lane = tid & 63;
    const int pillar = blockIdx.x * 4 + wv;
    const int bn = pillar / PIX;
    const int p  = pillar % PIX;
    const int yi = p / FW_;
    const int xi = p % FW_;

    __shared__ float w2s[C_ * D_];           // 16 KB, layout [c][d]
#pragma unroll
    for (int k = 0; k < 4; ++k)
        ((float4*)w2s)[k * 256 + tid] = ((const float4*)w2t)[k * 256 + tid];

    float h;
    {
        const size_t o = (size_t)pillar * C_ + lane;
        h = hpAll[o] + hpAll[NPOINT + o] + hpAll[2 * (size_t)NPOINT + o]
          + hpAll[3 * (size_t)NPOINT + o] + b1[lane];
        const float sc = gma[lane] / sqrtf(var[lane] + 1e-5f);
        h = (h - mu[lane]) * sc + bta[lane];
        h = h > 0.f ? h : 0.f;
    }
    __syncthreads();                          // w2s ready

    float l0 = 0.f, l1 = 0.f, l2 = 0.f, l3 = 0.f;
#pragma unroll
    for (int c = 0; c < C_; c += 4) {
        l0 += rlane_f(h, c + 0) * w2s[(c + 0) * D_ + lane];
        l1 += rlane_f(h, c + 1) * w2s[(c + 1) * D_ + lane];
        l2 += rlane_f(h, c + 2) * w2s[(c + 2) * D_ + lane];
        l3 += rlane_f(h, c + 3) * w2s[(c + 3) * D_ + lane];
    }
    const float logit = b2[lane] + ((l0 + l1) + (l2 + l3));

    float m = logit;
#pragma unroll
    for (int off = 32; off; off >>= 1) m = fmaxf(m, __shfl_xor(m, off));
    float e = expf(logit - m);
    float s = e;
#pragma unroll
    for (int off = 32; off; off >>= 1) s += __shfl_xor(s, off);

    const double* M = &Mbuf[bn * 9];
    const double xn = (double)xi * (703.0 / 43.0);
    const double yn = (double)yi * 17.0;
    const double vx = M[0] * xn + M[1] * yn + M[2];
    const double vy = M[3] * xn + M[4] * yn + M[5];
    const double dd = 1.0 + (double)lane * (59.0 / 63.0);
    const float* E = &extr[bn * 16];
    const double ex = dd * vx + (double)E[3];
    const double ey = dd * vy + (double)E[7];
    const int ix = (int)floor((ex + 51.2) * 1.25);
    const int iy = (int)floor((ey + 51.2) * 1.25);
    const bool valid = (ix >= 0) && (ix < BEVW) && (iy >= 0) && (iy < BEVH);

    const int i = pillar * D_ + lane;
    uint2 rec;
    rec.x = __float_as_uint(e / s);
    if (valid) {
        const int cell = (bn / N_) * BEVC + iy * BEVW + ix;
        const u32 rank = atomicAdd(&counts[cell], 1u);
        rec.y = (rank << 15) | (u32)cell;
    } else {
        rec.y = 0xFFFFFFFFu;
    }
    pc[i] = rec;
}

// ---------------------------------------------------------------------------
// K3: per-cell range allocation + fused selective spool-zero.
// Wave owns 64 consecutive cells; after the scan, a ballot marks cells that
// pool won't plain-store (empty or segment-spanning); the wave zeroes each
// flagged cell with one fully-coalesced 256B store (lane = channel).
// ---------------------------------------------------------------------------
__global__ __launch_bounds__(256) void k_alloc_zero(const u32* __restrict__ counts,
                                                    u32* __restrict__ offs,
                                                    u32* __restrict__ gcursor,
                                                    float* __restrict__ spool) {
    const int cell = blockIdx.x * 256 + threadIdx.x;
    const int lane = threadIdx.x & 63;
    const u32 len = counts[cell];
    u32 incl = len;
#pragma unroll
    for (int off = 1; off < 64; off <<= 1) {
        u32 t = __shfl_up(incl, off);
        if (lane >= off) incl += t;
    }
    u32 base = 0;
    if (lane == 63) base = atomicAdd(gcursor, incl);
    base = (u32)__shfl((int)base, 63);
    const u32 s = base + incl - len;
    offs[cell] = s;

    // fused selective zero (coalesced, one cell per iteration)
    const bool needzero = (len == 0u) || ((s >> 6) != ((s + len - 1) >> 6));
    u64 mask = __ballot(needzero);
    const int wavebase = cell - lane;         // first cell of this wave
    while (mask) {
        const int t = (int)__builtin_ctzll(mask);
        mask &= mask - 1ull;
        spool[(size_t)(wavebase + t) * C_ + lane] = 0.f;
    }
}

// ---------------------------------------------------------------------------
// K4: placement + sentinels. blocks [0,2112): place; block 2112: sentinels.
// ---------------------------------------------------------------------------
__global__ __launch_bounds__(256) void k_place(const uint2* __restrict__ pc,
                                               const u32* __restrict__ offs,
                                               const u32* __restrict__ gcursor,
                                               uint2* __restrict__ sorted,
                                               u32* __restrict__ offs_end) {
    const int blk = blockIdx.x;
    const int tid = threadIdx.x;
    if (blk < 2112) {
        const int i = blk * 256 + tid;        // < NPOINT exactly
        const uint2 rec = pc[i];
        if (rec.y != 0xFFFFFFFFu) {
            const u32 cell = rec.y & 0x7FFFu;
            const u32 rank = rec.y >> 15;
            const u32 pos  = offs[cell] + rank;
            uint2 o; o.x = rec.x; o.y = (cell << 14) | (u32)(i >> 6);
            sorted[pos] = o;
        }
    } else {
        const u32 total = *gcursor;
        if (tid < 128) {
            uint2 dummy; dummy.x = 0u; dummy.y = 0xFFFFFFFFu;
            sorted[total + tid] = dummy;
        }
        if (tid == 128) *offs_end = total;
    }
}

// ---------------------------------------------------------------------------
// K5: balanced segment pool -> spool (cell-major, coalesced 256B flushes),
// boundary ballot + 16-deep gather pipeline.
// ---------------------------------------------------------------------------
__global__ __launch_bounds__(256) void k_pool(const uint2* __restrict__ sorted,
                                              const u32* __restrict__ offsets,
                                              const float* __restrict__ x_t,
                                              float* __restrict__ spool) {
    const u32 P = offsets[NCELL];
    const int wv   = threadIdx.x >> 6;
    const int lane = threadIdx.x & 63;
    const u32 j0   = ((u32)blockIdx.x * 4u + (u32)wv) * 64u;
    if (j0 >= P) return;

    const uint2 pr  = sorted[j0 + (u32)lane];
    const float myw = __uint_as_float(pr.x);
    const int mycell = (int)(pr.y >> 14);
    int mypil = (int)(pr.y & 0x3FFFu);
    if (mypil >= NPILLAR) mypil = 0;          // dummy sentinel rows (w = 0)

    const int prev_cell = (j0 > 0) ? (int)(sorted[j0 - 1].y >> 14) : -1;
    const int next_cell = (int)(sorted[j0 + 64].y >> 14);

    const int upc = __shfl_up(mycell, 1);
    const u64 bm = __ballot(lane == 0 || mycell != upc);

    float xr[16];
#pragma unroll
    for (int t = 0; t < 16; ++t)
        xr[t] = x_t[(size_t)rlane_i(mypil, t) * C_ + lane];

    float acc = 0.f;
    bool first = true;

#pragma unroll
    for (int t = 0; t < 64; ++t) {
        acc += rlane_f(myw, t) * xr[t & 15];
        if (t + 16 < 64)
            xr[t & 15] = x_t[(size_t)rlane_i(mypil, t + 16) * C_ + lane];
        const bool flush = (t == 63) || ((bm >> (t + 1)) & 1ull);
        if (flush) {
            const int cc = rlane_i(mycell, t);
            if (cc < NCELL) {
                float* dst = spool + (size_t)cc * C_ + lane;   // coalesced
                const bool spans = (first && cc == prev_cell)
                                || (t == 63 && next_cell == cc);
                if (spans) atomicAdd(dst, acc);
                else *dst = acc;
            }
            acc = 0.f;
            first = false;
        }
    }
}

// ---------------------------------------------------------------------------
// K6: output transpose spool[b][cell][c] -> out[b][c][cell].
// ---------------------------------------------------------------------------
__global__ __launch_bounds__(256) void k_out(const float* __restrict__ spool,
                                             float* __restrict__ out) {
    const int tile_i = blockIdx.x;            // 0..511
    const int b  = tile_i >> 8;
    const int c0 = (tile_i & 255) * 64;       // cell base
    const int tid = threadIdx.x;
    const int lane = tid & 63;
    const int row4 = tid >> 6;

    __shared__ float tile[64][65];
#pragma unroll
    for (int k = 0; k < 16; ++k) {
        const int r = k * 4 + row4;
        tile[r][lane] = spool[((size_t)b * BEVC + c0 + r) * C_ + lane];
    }
    __syncthreads();
#pragma unroll
    for (int k = 0; k < 16; ++k) {
        const int ch = k * 4 + row4;
        out[((size_t)b * C_ + ch) * BEVC + c0 + lane] = tile[lane][ch];
    }
}

// ---------------------------------------------------------------------------
extern "C" void kernel_launch(void* const* d_in, const int* in_sizes, int n_in,
                              void* d_out, int out_size, void* d_ws, size_t ws_size,
                              hipStream_t stream) {
    const float* feat  = (const float*)d_in[0];
    const float* intr  = (const float*)d_in[1];
    const float* extr  = (const float*)d_in[2];
    const float* w1    = (const float*)d_in[3];
    const float* b1    = (const float*)d_in[4];
    const float* gma   = (const float*)d_in[5];
    const float* bta   = (const float*)d_in[6];
    const float* mu    = (const float*)d_in[7];
    const float* var   = (const float*)d_in[8];
    const float* w2    = (const float*)d_in[9];
    const float* b2    = (const float*)d_in[10];
    float* out = (float*)d_out;

    // workspace layout (8B-aligned first) — R14-proven
    double* Mbuf    = (double*)d_ws;                                 // 864 B
    u32*    gcursor = (u32*)((char*)d_ws + 960);
    uint2*  sorted  = (uint2*)((char*)d_ws + 1024);                  // NPOINT+128
    uint2*  pc      = sorted + NPOINT + 128;                         // NPOINT
    float*  x_t     = (float*)(pc + NPOINT);                         // NPOINT
    float*  hpAll   = x_t + NPOINT;                                  // 4*NPOINT
    u32*    counts  = (u32*)(hpAll + 4 * (size_t)NPOINT);            // NCELL
    u32*    offs    = counts + NCELL;                                // NCELL+1
    float*  w2t     = (float*)(offs + NCELL + 1);                    // 4096

    // spool (NCELL*64 floats = 8.39 MB) overlays hpAll (8.65 MB, dead after K2)
    float*  spool   = hpAll;

    k_init_conv<<<901, 256, 0, stream>>>(feat, w1, hpAll, x_t, w2, w2t,
                                         counts, gcursor, intr, extr, Mbuf);
    k_depth<<<NPILLAR / 4, 256, 0, stream>>>(hpAll, b1, gma, bta, mu, var,
                                             w2t, b2, Mbuf, extr, pc, counts);
    k_alloc_zero<<<NCELL / 256, 256, 0, stream>>>(counts, offs, gcursor, spool);
    k_place<<<2113, 256, 0, stream>>>(pc, offs, gcursor, sorted, &offs[NCELL]);
    k_pool<<<NPOINT / 64 / 4, 256, 0, stream>>>(sorted, offs, x_t, spool);
    k_out<<<512, 256, 0, stream>>>(spool, out);

    (void)in_sizes; (void)n_in; (void)ws_size; (void)out_size;
}